// Round 1
// 118.901 us; speedup vs baseline: 1.1109x; 1.1109x over previous
//
#include <hip/hip_runtime.h>
#include <stdint.h>

// Sizes: h (8,1024,512) f32, s (8,128,1024)->(1024,1024) f32,
//        Wh (512,128), Ws (1024,128), b,v (128,), out (8,128,1024) f32.
//
// Identity 1: tanh(ps+ph) = 1 - 2/(Eps*Eph + 1),
//   Eps = exp2(2*log2e*ps), Eph = exp2(2*log2e*ph); Eph exp'd in GEMM
//   epilogue, Eps exp'd in attn staging (combines split-K halves + bias).
// Identity 2: sum_a v_a/w_a over 4 terms shares ONE rcp (14 VALU + 1 rcp
//   per 4 reduction terms).
//
// R4 (this round): gemm_fused rebuilt for latency hiding.
//   - 640 UNIFORM blocks of exactly 16 k-steps (32 k each):
//       blocks 0..511  : Eph, 16 cols/block, K=512
//       blocks 512..639: Eps, 16 cols/block, split-K (2 halves of 512),
//                        raw partial sums -> psPart[half][a][ny]
//     (old: 288 blocks, 1.1 blk/CU = 1 wave/SIMD, Eps blocks a 2x-work tail)
//   - depth-4 register pipeline (statically rotated stage arrays under
//     full unroll) -> ~3 k-steps of global loads in flight vs 1.
//   - bias + half-combine + exp2 for Eps moved to attn staging (cheap).
//
// Pipeline:
//   1. transpose_cast : WhT[a][c], WsT[a][d] bf16 (k-contiguous A operands)
//   2. gemm_fused     : barrier-free register MFMA GEMM (above)
//   3. attn_softmax   : 512 blocks x 512 thr (R3 shape — best measured),
//                       2y x 2x per thread, 4-term rcp sharing.

typedef float  f32x4  __attribute__((ext_vector_type(4)));
typedef __bf16 bf16x8 __attribute__((ext_vector_type(8)));

#define LOG2E     1.4426950408889634f
#define TWO_LOG2E 2.8853900817779268f

// ------------------------------------------------- weight transpose + cast
__global__ void __launch_bounds__(256) transpose_cast(
    const float* __restrict__ Wh, const float* __restrict__ Ws,
    __bf16* __restrict__ WhT, __bf16* __restrict__ WsT)
{
    int bid = blockIdx.x;  // 0..7 -> Wh tiles, 8..23 -> Ws tiles
    const float* src; __bf16* dst; int K, c0;
    if (bid < 8) { src = Wh; dst = WhT; K = 512;  c0 = bid * 64; }
    else         { src = Ws; dst = WsT; K = 1024; c0 = (bid - 8) * 64; }
    __shared__ float tile[64][129];
    int t = threadIdx.x;
    for (int i = 0; i < 8192; i += 256) {
        int idx = i + t;
        int r = idx >> 7, col = idx & 127;              // 64 rows(c) x 128 cols(a)
        tile[r][col] = src[(size_t)(c0 + r) * 128 + col];
    }
    __syncthreads();
    for (int i = 0; i < 8192; i += 256) {
        int idx = i + t;
        int a = idx >> 6, cc = idx & 63;                // 128 rows(a) x 64 cols(c)
        dst[(size_t)a * K + c0 + cc] = (__bf16)tile[cc][a];
    }
}

// --------------------------------------- barrier-free register MFMA GEMM
// 640 uniform blocks, 256 thr (4 waves). Wave w owns rows mq=w*32
// (2 m-tiles of 16) x the block's 16 cols. Exactly 16 k-steps of 32.
// blocks 0..511  : Eph  (A=WhT 128x512,  B=h,  colg=bid*16, exp2 epilogue)
// blocks 512..639: Eps  (A=WsT 128x1024, B=s,  split-K half=bit0,
//                        colg=((bid-512)>>1)*16, RAW store to psPart)
__global__ void __launch_bounds__(256) gemm_fused(
    const __bf16* __restrict__ WhT, const __bf16* __restrict__ WsT,
    const float* __restrict__ h, const float* __restrict__ s,
    float* __restrict__ Eph, float* __restrict__ psPart)
{
    int bid = blockIdx.x;
    int tid = threadIdx.x, lane = tid & 63, w = tid >> 6;
    int mq = w * 32;
    int q = lane >> 4, c = lane & 15;

    const __bf16* A; const float* B; float* Cp; int K, kbase, colg; bool isPs;
    if (bid < 512) {
        isPs = false; A = WhT; B = h; K = 512; kbase = 0;
        colg = bid * 16;
        int n = colg >> 10, x = colg & 1023;
        Cp = Eph + (size_t)n * 131072 + x;     // + m*1024 + col in epilogue
    } else {
        isPs = true; A = WsT; B = s; K = 1024;
        int b2 = bid - 512;
        int half = b2 & 1; kbase = half * 512;
        colg = (b2 >> 1) * 16;
        Cp = psPart + (size_t)half * 131072 + colg;
    }

    const float*  Bp = B + (size_t)(colg + c) * K + kbase + q * 8;
    const __bf16* Ap = A + (size_t)(mq + c) * K + kbase + q * 8;

    f32x4 acc0 = {}, acc1 = {};
    float4 b0s[4], b1s[4];
    bf16x8 a0s[4], a1s[4];
    #pragma unroll
    for (int p = 0; p < 4; ++p) {              // prologue: 4 stages in flight
        int k = p * 32;
        b0s[p] = *(const float4*)(Bp + k);
        b1s[p] = *(const float4*)(Bp + k + 4);
        a0s[p] = *(const bf16x8*)(Ap + k);
        a1s[p] = *(const bf16x8*)(Ap + (size_t)16 * K + k);
    }
    #pragma unroll
    for (int it = 0; it < 16; ++it) {          // fully unrolled: static %4
        int cur = it & 3;
        float4 b0 = b0s[cur], b1 = b1s[cur];
        bf16x8 bf;
        bf[0] = (__bf16)b0.x; bf[1] = (__bf16)b0.y;
        bf[2] = (__bf16)b0.z; bf[3] = (__bf16)b0.w;
        bf[4] = (__bf16)b1.x; bf[5] = (__bf16)b1.y;
        bf[6] = (__bf16)b1.z; bf[7] = (__bf16)b1.w;
        acc0 = __builtin_amdgcn_mfma_f32_16x16x32_bf16(a0s[cur], bf, acc0, 0, 0, 0);
        acc1 = __builtin_amdgcn_mfma_f32_16x16x32_bf16(a1s[cur], bf, acc1, 0, 0, 0);
        if (it + 4 < 16) {                     // refill freed stage slot
            int k = (it + 4) * 32;
            b0s[cur] = *(const float4*)(Bp + k);
            b1s[cur] = *(const float4*)(Bp + k + 4);
            a0s[cur] = *(const bf16x8*)(Ap + k);
            a1s[cur] = *(const bf16x8*)(Ap + (size_t)16 * K + k);
        }
    }

    // C/D layout: col=lane&15, row(within 16-tile)=q*4+r  (m89-verified)
    #pragma unroll
    for (int i = 0; i < 2; ++i) {
        f32x4 av = i ? acc1 : acc0;
        #pragma unroll
        for (int r = 0; r < 4; ++r) {
            int m = mq + i * 16 + q * 4 + r;
            if (isPs) Cp[(size_t)m * 1024 + c] = av[r];
            else      Cp[(size_t)m * 1024 + c] =
                          __builtin_amdgcn_exp2f(av[r] * TWO_LOG2E);
        }
    }
}

// ------------------------------------------- fused tanh-dot + softmax
// block = (n, y-pair), 512 threads; thread t owns x = {2t, 2t+1}, 2 y-rows.
// acc[y][xi] = sum_a v_a * rcp(w_a),  w_a = fma(Eps_y[a], Eph[a][x], 1)
// computed 4 a-terms per rcp via rational-sum merging.
// Staging now combines the two split-K Eps halves + bias + exp2.
__global__ void __launch_bounds__(512) attn_softmax(
    const float* __restrict__ Eph, const float* __restrict__ psPart,
    const float* __restrict__ bias, const float* __restrict__ v,
    float* __restrict__ out)
{
    int bid = blockIdx.x;            // 512 blocks = n(8) x yg(64)
    int n = bid >> 6, yg = bid & 63;
    int ny = n * 128 + yg * 2;       // 2 consecutive global rows
    const float2* ph2 = (const float2*)(Eph + (size_t)n * 131072);
    int t = threadIdx.x;

    __shared__ float4 pv_s[128];     // {Eps[y0][a], Eps[y1][a], v[a], 0}
    __shared__ float wred[2][8];
    __shared__ float VsumS;

    if (t < 128) {
        float2 pa = *(const float2*)(psPart + (size_t)t * 1024 + ny);
        float2 pb = *(const float2*)(psPart + 131072 + (size_t)t * 1024 + ny);
        float bb = bias[t];
        float4 pk;
        pk.x = __builtin_amdgcn_exp2f((pa.x + pb.x + bb) * TWO_LOG2E);
        pk.y = __builtin_amdgcn_exp2f((pa.y + pb.y + bb) * TWO_LOG2E);
        pk.z = v[t]; pk.w = 0.f;
        pv_s[t] = pk;
    }
    if (t >= 448) {                  // last wave computes Vsum (disjoint)
        int l = t - 448;
        float vv = v[l] + v[l + 64];
        for (int m = 32; m; m >>= 1) vv += __shfl_xor(vv, m);
        if (l == 0) VsumS = vv;
    }
    __syncthreads();
    float Vsum = VsumS;

    float acc00 = 0.f, acc01 = 0.f, acc10 = 0.f, acc11 = 0.f;
    #pragma unroll 2
    for (int a = 0; a < 128; a += 4) {
        float4 q0 = pv_s[a + 0], q1 = pv_s[a + 1];
        float4 q2 = pv_s[a + 2], q3 = pv_s[a + 3];
        float2 p0 = ph2[(a + 0) * 512 + t];
        float2 p1 = ph2[(a + 1) * 512 + t];
        float2 p2 = ph2[(a + 2) * 512 + t];
        float2 p3 = ph2[(a + 3) * 512 + t];
        // one output (y fixed via eps args, x fixed via ph args):
        // 4-term rational sum: 14 VALU + 1 rcp
        auto comb = [&](float e0, float e1, float e2, float e3,
                        float h0, float h1, float h2, float h3, float& acc) {
            float w0 = fmaf(e0, h0, 1.f);
            float w1 = fmaf(e1, h1, 1.f);
            float w2 = fmaf(e2, h2, 1.f);
            float w3 = fmaf(e3, h3, 1.f);
            float d01 = w0 * w1, d23 = w2 * w3;
            float n01 = fmaf(q1.z, w0, q0.z * w1);
            float n23 = fmaf(q3.z, w2, q2.z * w3);
            float dd = d01 * d23;
            float nn = fmaf(n23, d01, n01 * d23);
            acc = fmaf(nn, __builtin_amdgcn_rcpf(dd), acc);
        };
        comb(q0.x, q1.x, q2.x, q3.x, p0.x, p1.x, p2.x, p3.x, acc00);
        comb(q0.x, q1.x, q2.x, q3.x, p0.y, p1.y, p2.y, p3.y, acc01);
        comb(q0.y, q1.y, q2.y, q3.y, p0.x, p1.x, p2.x, p3.x, acc10);
        comb(q0.y, q1.y, q2.y, q3.y, p0.y, p1.y, p2.y, p3.y, acc11);
    }
    float e00 = fmaf(-2.f, acc00, Vsum);
    float e01 = fmaf(-2.f, acc01, Vsum);
    float e10 = fmaf(-2.f, acc10, Vsum);
    float e11 = fmaf(-2.f, acc11, Vsum);

    int lane = t & 63, wv = t >> 6;
    float mx0 = fmaxf(e00, e01), mx1 = fmaxf(e10, e11);
    for (int m = 32; m; m >>= 1) {
        mx0 = fmaxf(mx0, __shfl_xor(mx0, m));
        mx1 = fmaxf(mx1, __shfl_xor(mx1, m));
    }
    if (lane == 0) { wred[0][wv] = mx0; wred[1][wv] = mx1; }
    __syncthreads();
    mx0 = wred[0][0]; mx1 = wred[1][0];
    #pragma unroll
    for (int i = 1; i < 8; ++i) {
        mx0 = fmaxf(mx0, wred[0][i]);
        mx1 = fmaxf(mx1, wred[1][i]);
    }
    __syncthreads();
    float s00 = __builtin_amdgcn_exp2f((e00 - mx0) * LOG2E);
    float s01 = __builtin_amdgcn_exp2f((e01 - mx0) * LOG2E);
    float s10 = __builtin_amdgcn_exp2f((e10 - mx1) * LOG2E);
    float s11 = __builtin_amdgcn_exp2f((e11 - mx1) * LOG2E);
    float sm0 = s00 + s01, sm1 = s10 + s11;
    for (int m = 32; m; m >>= 1) {
        sm0 += __shfl_xor(sm0, m);
        sm1 += __shfl_xor(sm1, m);
    }
    if (lane == 0) { wred[0][wv] = sm0; wred[1][wv] = sm1; }
    __syncthreads();
    sm0 = 0.f; sm1 = 0.f;
    #pragma unroll
    for (int i = 0; i < 8; ++i) { sm0 += wred[0][i]; sm1 += wred[1][i]; }
    float r0 = __builtin_amdgcn_rcpf(sm0);
    float r1 = __builtin_amdgcn_rcpf(sm1);
    float2 o0; o0.x = s00 * r0; o0.y = s01 * r0;
    float2 o1; o1.x = s10 * r1; o1.y = s11 * r1;
    ((float2*)(out + (size_t)(ny + 0) * 1024))[t] = o0;
    ((float2*)(out + (size_t)(ny + 1) * 1024))[t] = o1;
}

// ----------------------------------------------------------------- launcher
extern "C" void kernel_launch(void* const* d_in, const int* in_sizes, int n_in,
                              void* d_out, int out_size, void* d_ws, size_t ws_size,
                              hipStream_t stream) {
    const float* h  = (const float*)d_in[0];
    const float* s  = (const float*)d_in[1];
    const float* Wh = (const float*)d_in[2];
    const float* Ws = (const float*)d_in[3];
    const float* b  = (const float*)d_in[4];
    const float* v  = (const float*)d_in[5];
    float* out = (float*)d_out;

    char* ws = (char*)d_ws;
    float*  Eph    = (float*)ws;                               // 4 MB
    float*  psPart = (float*)(ws + (4u << 20));                // 1 MB (2 halves)
    __bf16* WhT    = (__bf16*)(ws + (5u << 20));               // 128 KB
    __bf16* WsT    = WhT + (size_t)128 * 512;                  // 256 KB

    transpose_cast<<<24, 256, 0, stream>>>(Wh, Ws, WhT, WsT);
    gemm_fused<<<640, 256, 0, stream>>>(WhT, WsT, h, s, Eph, psPart);
    attn_softmax<<<512, 512, 0, stream>>>(Eph, psPart, b, v, out);
}

// Round 2
// 116.530 us; speedup vs baseline: 1.1335x; 1.0203x over previous
//
#include <hip/hip_runtime.h>
#include <stdint.h>

// Sizes: h (8,1024,512) f32, s (8,128,1024)->(1024,1024) f32,
//        Wh (512,128), Ws (1024,128), b,v (128,), out (8,128,1024) f32.
//
// Identity 1: tanh(ps+ph) = 1 - 2/(Eps*Eph + 1),
//   Eps = exp2(2*log2e*ps), Eph = exp2(2*log2e*ph); Eph exp'd in GEMM
//   epilogue, Eps exp'd in attn staging (combines split-K halves + bias).
// Identity 2: sum_a v_a/w_a over 4 terms shares ONE rcp (14 VALU + 1 rcp
//   per 4 reduction terms).
//
// R5 (this round): attn was L2-bound (268 MB Eph re-reads, per-XCD working
// set == 4 MB L2). Fix:
//   - attn: 256 blocks x 512 thr, 4 y-rows x 2 x per thread -> Eph L2
//     traffic halves (134 MB); n-major block->XCD map (n = bid&7) keeps
//     each XCD's Eph slice at 512 KB (L2-hot); prefetch ph (global) and
//     eps (LDS) one iteration ahead (2 waves/SIMD needs the ILP).
//   - transpose_cast: 96 blocks (16-row tiles) vs 24 — latency-bound fix.
//   - gemm_fused: unchanged (at its ~25 MB HBM floor).
//
// Pipeline:
//   1. transpose_cast : WhT[a][c], WsT[a][d] bf16 (k-contiguous A operands)
//   2. gemm_fused     : barrier-free register MFMA GEMM, 640 uniform blocks,
//                       depth-4 register pipeline, split-K for Eps
//   3. attn_softmax   : fused tanh-dot + softmax (above)

typedef float  f32x4  __attribute__((ext_vector_type(4)));
typedef __bf16 bf16x8 __attribute__((ext_vector_type(8)));

#define LOG2E     1.4426950408889634f
#define TWO_LOG2E 2.8853900817779268f

// ------------------------------------------------- weight transpose + cast
__global__ void __launch_bounds__(256) transpose_cast(
    const float* __restrict__ Wh, const float* __restrict__ Ws,
    __bf16* __restrict__ WhT, __bf16* __restrict__ WsT)
{
    int bid = blockIdx.x;  // 0..31 -> Wh tiles (512/16), 32..95 -> Ws (1024/16)
    const float* src; __bf16* dst; int K, c0;
    if (bid < 32) { src = Wh; dst = WhT; K = 512;  c0 = bid * 16; }
    else          { src = Ws; dst = WsT; K = 1024; c0 = (bid - 32) * 16; }
    __shared__ float tile[16][129];
    int t = threadIdx.x;
    #pragma unroll
    for (int i = 0; i < 2048; i += 256) {
        int idx = i + t;
        int r = idx >> 7, col = idx & 127;              // 16 rows(c) x 128 cols(a)
        tile[r][col] = src[(size_t)(c0 + r) * 128 + col];
    }
    __syncthreads();
    #pragma unroll
    for (int i = 0; i < 2048; i += 256) {
        int idx = i + t;
        int a = idx >> 4, cc = idx & 15;                // 128 rows(a) x 16 cols(c)
        dst[(size_t)a * K + c0 + cc] = (__bf16)tile[cc][a];
    }
}

// --------------------------------------- barrier-free register MFMA GEMM
// 640 uniform blocks, 256 thr (4 waves). Wave w owns rows mq=w*32
// (2 m-tiles of 16) x the block's 16 cols. Exactly 16 k-steps of 32.
// blocks 0..511  : Eph  (A=WhT 128x512,  B=h,  colg=bid*16, exp2 epilogue)
// blocks 512..639: Eps  (A=WsT 128x1024, B=s,  split-K half=bit0,
//                        colg=((bid-512)>>1)*16, RAW store to psPart)
__global__ void __launch_bounds__(256) gemm_fused(
    const __bf16* __restrict__ WhT, const __bf16* __restrict__ WsT,
    const float* __restrict__ h, const float* __restrict__ s,
    float* __restrict__ Eph, float* __restrict__ psPart)
{
    int bid = blockIdx.x;
    int tid = threadIdx.x, lane = tid & 63, w = tid >> 6;
    int mq = w * 32;
    int q = lane >> 4, c = lane & 15;

    const __bf16* A; const float* B; float* Cp; int K, kbase, colg; bool isPs;
    if (bid < 512) {
        isPs = false; A = WhT; B = h; K = 512; kbase = 0;
        colg = bid * 16;
        int n = colg >> 10, x = colg & 1023;
        Cp = Eph + (size_t)n * 131072 + x;     // + m*1024 + col in epilogue
    } else {
        isPs = true; A = WsT; B = s; K = 1024;
        int b2 = bid - 512;
        int half = b2 & 1; kbase = half * 512;
        colg = (b2 >> 1) * 16;
        Cp = psPart + (size_t)half * 131072 + colg;
    }

    const float*  Bp = B + (size_t)(colg + c) * K + kbase + q * 8;
    const __bf16* Ap = A + (size_t)(mq + c) * K + kbase + q * 8;

    f32x4 acc0 = {}, acc1 = {};
    float4 b0s[4], b1s[4];
    bf16x8 a0s[4], a1s[4];
    #pragma unroll
    for (int p = 0; p < 4; ++p) {              // prologue: 4 stages in flight
        int k = p * 32;
        b0s[p] = *(const float4*)(Bp + k);
        b1s[p] = *(const float4*)(Bp + k + 4);
        a0s[p] = *(const bf16x8*)(Ap + k);
        a1s[p] = *(const bf16x8*)(Ap + (size_t)16 * K + k);
    }
    #pragma unroll
    for (int it = 0; it < 16; ++it) {          // fully unrolled: static %4
        int cur = it & 3;
        float4 b0 = b0s[cur], b1 = b1s[cur];
        bf16x8 bf;
        bf[0] = (__bf16)b0.x; bf[1] = (__bf16)b0.y;
        bf[2] = (__bf16)b0.z; bf[3] = (__bf16)b0.w;
        bf[4] = (__bf16)b1.x; bf[5] = (__bf16)b1.y;
        bf[6] = (__bf16)b1.z; bf[7] = (__bf16)b1.w;
        acc0 = __builtin_amdgcn_mfma_f32_16x16x32_bf16(a0s[cur], bf, acc0, 0, 0, 0);
        acc1 = __builtin_amdgcn_mfma_f32_16x16x32_bf16(a1s[cur], bf, acc1, 0, 0, 0);
        if (it + 4 < 16) {                     // refill freed stage slot
            int k = (it + 4) * 32;
            b0s[cur] = *(const float4*)(Bp + k);
            b1s[cur] = *(const float4*)(Bp + k + 4);
            a0s[cur] = *(const bf16x8*)(Ap + k);
            a1s[cur] = *(const bf16x8*)(Ap + (size_t)16 * K + k);
        }
    }

    // C/D layout: col=lane&15, row(within 16-tile)=q*4+r  (m89-verified)
    #pragma unroll
    for (int i = 0; i < 2; ++i) {
        f32x4 av = i ? acc1 : acc0;
        #pragma unroll
        for (int r = 0; r < 4; ++r) {
            int m = mq + i * 16 + q * 4 + r;
            if (isPs) Cp[(size_t)m * 1024 + c] = av[r];
            else      Cp[(size_t)m * 1024 + c] =
                          __builtin_amdgcn_exp2f(av[r] * TWO_LOG2E);
        }
    }
}

// ------------------------------------------- fused tanh-dot + softmax
// 256 blocks (n = bid&7 -> XCD-major: each XCD touches one 512 KB Eph[n]
// slice only), 512 threads; thread t owns x = {2t, 2t+1} and 4 y-rows.
// acc[y][xi] = sum_a v_a * rcp(w_a),  w_a = fma(Eps_y[a], Eph[a][x], 1)
// computed 4 a-terms per rcp via rational-sum merging.
// Staging combines the two split-K Eps halves + bias + exp2 for 4 rows.
__global__ void __launch_bounds__(512) attn_softmax(
    const float* __restrict__ Eph, const float* __restrict__ psPart,
    const float* __restrict__ bias, const float* __restrict__ v,
    float* __restrict__ out)
{
    int bid = blockIdx.x;            // 256 blocks = yg(32) x n(8), n minor
    int n = bid & 7, yg = bid >> 3;
    int ny = n * 128 + yg * 4;       // 4 consecutive global rows
    const float2* ph2 = (const float2*)(Eph + (size_t)n * 131072);
    int t = threadIdx.x;

    __shared__ f32x4 eps4[128];      // {Eps[y0..y3][a]}
    __shared__ f32x4 vv4[32];        // v[a] as float4
    __shared__ float wred[4][8];
    __shared__ float VsumS;

    if (t < 128) {
        f32x4 pa = *(const f32x4*)(psPart + (size_t)t * 1024 + ny);
        f32x4 pb = *(const f32x4*)(psPart + 131072 + (size_t)t * 1024 + ny);
        float bb = bias[t];
        f32x4 pk;
        #pragma unroll
        for (int j = 0; j < 4; ++j)
            pk[j] = __builtin_amdgcn_exp2f((pa[j] + pb[j] + bb) * TWO_LOG2E);
        eps4[t] = pk;
    } else if (t < 160) {
        vv4[t - 128] = *(const f32x4*)(v + (t - 128) * 4);
    }
    if (t >= 448) {                  // last wave computes Vsum (disjoint)
        int l = t - 448;
        float vv = v[l] + v[l + 64];
        for (int m = 32; m; m >>= 1) vv += __shfl_xor(vv, m);
        if (l == 0) VsumS = vv;
    }
    __syncthreads();
    float Vsum = VsumS;

    float acc[4][2] = {};
    float2 p[4]; f32x4 q[4]; f32x4 vr;
    #pragma unroll
    for (int i = 0; i < 4; ++i) p[i] = ph2[i * 512 + t];
    #pragma unroll
    for (int i = 0; i < 4; ++i) q[i] = eps4[i];
    vr = vv4[0];

    // 4-term rational sum: 14 VALU + 1 rcp for one output, 4 a-terms
    auto comb = [&](float e0, float e1, float e2, float e3,
                    float h0, float h1, float h2, float h3,
                    float v0, float v1, float v2, float v3, float& a_) {
        float w0 = fmaf(e0, h0, 1.f);
        float w1 = fmaf(e1, h1, 1.f);
        float w2 = fmaf(e2, h2, 1.f);
        float w3 = fmaf(e3, h3, 1.f);
        float d01 = w0 * w1, d23 = w2 * w3;
        float n01 = fmaf(v1, w0, v0 * w1);
        float n23 = fmaf(v3, w2, v2 * w3);
        float dd = d01 * d23;
        float nn = fmaf(n23, d01, n01 * d23);
        a_ = fmaf(nn, __builtin_amdgcn_rcpf(dd), a_);
    };

    #pragma unroll 2
    for (int a = 0; a < 128; a += 4) {
        int an = (a + 4 < 128) ? a + 4 : a;          // prefetch next iter
        float2 np[4]; f32x4 nq[4];
        #pragma unroll
        for (int i = 0; i < 4; ++i) np[i] = ph2[(an + i) * 512 + t];
        #pragma unroll
        for (int i = 0; i < 4; ++i) nq[i] = eps4[an + i];
        f32x4 nvr = vv4[an >> 2];

        #pragma unroll
        for (int j = 0; j < 4; ++j) {
            comb(q[0][j], q[1][j], q[2][j], q[3][j],
                 p[0].x, p[1].x, p[2].x, p[3].x,
                 vr[0], vr[1], vr[2], vr[3], acc[j][0]);
            comb(q[0][j], q[1][j], q[2][j], q[3][j],
                 p[0].y, p[1].y, p[2].y, p[3].y,
                 vr[0], vr[1], vr[2], vr[3], acc[j][1]);
        }
        #pragma unroll
        for (int i = 0; i < 4; ++i) { p[i] = np[i]; q[i] = nq[i]; }
        vr = nvr;
    }

    float e[4][2];
    #pragma unroll
    for (int j = 0; j < 4; ++j) {
        e[j][0] = fmaf(-2.f, acc[j][0], Vsum);
        e[j][1] = fmaf(-2.f, acc[j][1], Vsum);
    }

    int lane = t & 63, wv = t >> 6;
    float mx[4];
    #pragma unroll
    for (int j = 0; j < 4; ++j) {
        mx[j] = fmaxf(e[j][0], e[j][1]);
        for (int m = 32; m; m >>= 1) mx[j] = fmaxf(mx[j], __shfl_xor(mx[j], m));
    }
    if (lane == 0) {
        #pragma unroll
        for (int j = 0; j < 4; ++j) wred[j][wv] = mx[j];
    }
    __syncthreads();
    #pragma unroll
    for (int j = 0; j < 4; ++j) {
        mx[j] = wred[j][0];
        #pragma unroll
        for (int i = 1; i < 8; ++i) mx[j] = fmaxf(mx[j], wred[j][i]);
    }
    __syncthreads();
    float sx[4][2], sm[4];
    #pragma unroll
    for (int j = 0; j < 4; ++j) {
        sx[j][0] = __builtin_amdgcn_exp2f((e[j][0] - mx[j]) * LOG2E);
        sx[j][1] = __builtin_amdgcn_exp2f((e[j][1] - mx[j]) * LOG2E);
        sm[j] = sx[j][0] + sx[j][1];
        for (int m = 32; m; m >>= 1) sm[j] += __shfl_xor(sm[j], m);
    }
    if (lane == 0) {
        #pragma unroll
        for (int j = 0; j < 4; ++j) wred[j][wv] = sm[j];
    }
    __syncthreads();
    #pragma unroll
    for (int j = 0; j < 4; ++j) {
        float smj = 0.f;
        #pragma unroll
        for (int i = 0; i < 8; ++i) smj += wred[j][i];
        float r = __builtin_amdgcn_rcpf(smj);
        float2 o; o.x = sx[j][0] * r; o.y = sx[j][1] * r;
        ((float2*)(out + (size_t)(ny + j) * 1024))[t] = o;
    }
}

// ----------------------------------------------------------------- launcher
extern "C" void kernel_launch(void* const* d_in, const int* in_sizes, int n_in,
                              void* d_out, int out_size, void* d_ws, size_t ws_size,
                              hipStream_t stream) {
    const float* h  = (const float*)d_in[0];
    const float* s  = (const float*)d_in[1];
    const float* Wh = (const float*)d_in[2];
    const float* Ws = (const float*)d_in[3];
    const float* b  = (const float*)d_in[4];
    const float* v  = (const float*)d_in[5];
    float* out = (float*)d_out;

    char* ws = (char*)d_ws;
    float*  Eph    = (float*)ws;                               // 4 MB
    float*  psPart = (float*)(ws + (4u << 20));                // 1 MB (2 halves)
    __bf16* WhT    = (__bf16*)(ws + (5u << 20));               // 128 KB
    __bf16* WsT    = WhT + (size_t)128 * 512;                  // 256 KB

    transpose_cast<<<96, 256, 0, stream>>>(Wh, Ws, WhT, WsT);
    gemm_fused<<<640, 256, 0, stream>>>(WhT, WsT, h, s, Eph, psPart);
    attn_softmax<<<256, 512, 0, stream>>>(Eph, psPart, b, v, out);
}

// Round 3
// 111.788 us; speedup vs baseline: 1.1816x; 1.0424x over previous
//
#include <hip/hip_runtime.h>
#include <stdint.h>

// Sizes: h (8,1024,512) f32, s (8,128,1024)->(1024,1024) f32,
//        Wh (512,128), Ws (1024,128), b,v (128,), out (8,128,1024) f32.
//
// Identity 1: tanh(ps+ph) = 1 - 2/(Eps*Eph + 1),
//   Eps = exp2(2*log2e*ps), Eph = exp2(2*log2e*ph); Eph exp'd in GEMM
//   epilogue, Eps exp'd in attn staging (combines split-K halves + bias).
// Identity 2: sum_a v_a/w_a over 4 terms shares ONE rcp (14 VALU + 1 rcp
//   per 4 reduction terms) — verified to be the algebraic floor for this
//   expression shape (alternate stagings all re-derive to 14).
//
// R6 (this round): attn comb vectorized over the thread's x-pair via
//   ext_vector_type(2) float + __builtin_elementwise_fma -> v_pk_fma_f32 /
//   v_pk_mul_f32. Identical arithmetic (fma-for-fma, same rcp count);
//   pure A/B probe of gfx950's packed-f32 issue rate. If full-rate,
//   attn VALU issue drops ~40%.
//
// Pipeline:
//   1. transpose_cast : WhT[a][c], WsT[a][d] bf16 (k-contiguous A operands)
//   2. gemm_fused     : barrier-free register MFMA GEMM, 640 uniform blocks,
//                       depth-4 register pipeline, split-K for Eps
//   3. attn_softmax   : fused tanh-dot + softmax, 256 blocks x 512 thr,
//                       n-major XCD map, 4y x 2x per thread (x-pair packed)

typedef float  f32x4  __attribute__((ext_vector_type(4)));
typedef float  f32x2  __attribute__((ext_vector_type(2)));
typedef __bf16 bf16x8 __attribute__((ext_vector_type(8)));

#define LOG2E     1.4426950408889634f
#define TWO_LOG2E 2.8853900817779268f

static __device__ __forceinline__ f32x2 sp2(float s) {
    return (f32x2){s, s};
}

// ------------------------------------------------- weight transpose + cast
__global__ void __launch_bounds__(256) transpose_cast(
    const float* __restrict__ Wh, const float* __restrict__ Ws,
    __bf16* __restrict__ WhT, __bf16* __restrict__ WsT)
{
    int bid = blockIdx.x;  // 0..31 -> Wh tiles (512/16), 32..95 -> Ws (1024/16)
    const float* src; __bf16* dst; int K, c0;
    if (bid < 32) { src = Wh; dst = WhT; K = 512;  c0 = bid * 16; }
    else          { src = Ws; dst = WsT; K = 1024; c0 = (bid - 32) * 16; }
    __shared__ float tile[16][129];
    int t = threadIdx.x;
    #pragma unroll
    for (int i = 0; i < 2048; i += 256) {
        int idx = i + t;
        int r = idx >> 7, col = idx & 127;              // 16 rows(c) x 128 cols(a)
        tile[r][col] = src[(size_t)(c0 + r) * 128 + col];
    }
    __syncthreads();
    #pragma unroll
    for (int i = 0; i < 2048; i += 256) {
        int idx = i + t;
        int a = idx >> 4, cc = idx & 15;                // 128 rows(a) x 16 cols(c)
        dst[(size_t)a * K + c0 + cc] = (__bf16)tile[cc][a];
    }
}

// --------------------------------------- barrier-free register MFMA GEMM
// 640 uniform blocks, 256 thr (4 waves). Wave w owns rows mq=w*32
// (2 m-tiles of 16) x the block's 16 cols. Exactly 16 k-steps of 32.
// blocks 0..511  : Eph  (A=WhT 128x512,  B=h,  colg=bid*16, exp2 epilogue)
// blocks 512..639: Eps  (A=WsT 128x1024, B=s,  split-K half=bit0,
//                        colg=((bid-512)>>1)*16, RAW store to psPart)
__global__ void __launch_bounds__(256) gemm_fused(
    const __bf16* __restrict__ WhT, const __bf16* __restrict__ WsT,
    const float* __restrict__ h, const float* __restrict__ s,
    float* __restrict__ Eph, float* __restrict__ psPart)
{
    int bid = blockIdx.x;
    int tid = threadIdx.x, lane = tid & 63, w = tid >> 6;
    int mq = w * 32;
    int q = lane >> 4, c = lane & 15;

    const __bf16* A; const float* B; float* Cp; int K, kbase, colg; bool isPs;
    if (bid < 512) {
        isPs = false; A = WhT; B = h; K = 512; kbase = 0;
        colg = bid * 16;
        int n = colg >> 10, x = colg & 1023;
        Cp = Eph + (size_t)n * 131072 + x;     // + m*1024 + col in epilogue
    } else {
        isPs = true; A = WsT; B = s; K = 1024;
        int b2 = bid - 512;
        int half = b2 & 1; kbase = half * 512;
        colg = (b2 >> 1) * 16;
        Cp = psPart + (size_t)half * 131072 + colg;
    }

    const float*  Bp = B + (size_t)(colg + c) * K + kbase + q * 8;
    const __bf16* Ap = A + (size_t)(mq + c) * K + kbase + q * 8;

    f32x4 acc0 = {}, acc1 = {};
    float4 b0s[4], b1s[4];
    bf16x8 a0s[4], a1s[4];
    #pragma unroll
    for (int p = 0; p < 4; ++p) {              // prologue: 4 stages in flight
        int k = p * 32;
        b0s[p] = *(const float4*)(Bp + k);
        b1s[p] = *(const float4*)(Bp + k + 4);
        a0s[p] = *(const bf16x8*)(Ap + k);
        a1s[p] = *(const bf16x8*)(Ap + (size_t)16 * K + k);
    }
    #pragma unroll
    for (int it = 0; it < 16; ++it) {          // fully unrolled: static %4
        int cur = it & 3;
        float4 b0 = b0s[cur], b1 = b1s[cur];
        bf16x8 bf;
        bf[0] = (__bf16)b0.x; bf[1] = (__bf16)b0.y;
        bf[2] = (__bf16)b0.z; bf[3] = (__bf16)b0.w;
        bf[4] = (__bf16)b1.x; bf[5] = (__bf16)b1.y;
        bf[6] = (__bf16)b1.z; bf[7] = (__bf16)b1.w;
        acc0 = __builtin_amdgcn_mfma_f32_16x16x32_bf16(a0s[cur], bf, acc0, 0, 0, 0);
        acc1 = __builtin_amdgcn_mfma_f32_16x16x32_bf16(a1s[cur], bf, acc1, 0, 0, 0);
        if (it + 4 < 16) {                     // refill freed stage slot
            int k = (it + 4) * 32;
            b0s[cur] = *(const float4*)(Bp + k);
            b1s[cur] = *(const float4*)(Bp + k + 4);
            a0s[cur] = *(const bf16x8*)(Ap + k);
            a1s[cur] = *(const bf16x8*)(Ap + (size_t)16 * K + k);
        }
    }

    // C/D layout: col=lane&15, row(within 16-tile)=q*4+r  (m89-verified)
    #pragma unroll
    for (int i = 0; i < 2; ++i) {
        f32x4 av = i ? acc1 : acc0;
        #pragma unroll
        for (int r = 0; r < 4; ++r) {
            int m = mq + i * 16 + q * 4 + r;
            if (isPs) Cp[(size_t)m * 1024 + c] = av[r];
            else      Cp[(size_t)m * 1024 + c] =
                          __builtin_amdgcn_exp2f(av[r] * TWO_LOG2E);
        }
    }
}

// ------------------------------------------- fused tanh-dot + softmax
// 256 blocks (n = bid&7 -> XCD-major: each XCD touches one 512 KB Eph[n]
// slice only), 512 threads; thread t owns x = {2t, 2t+1} and 4 y-rows.
// acc[y] (f32x2 over the x-pair) = sum_a v_a * rcp(w_a),
//   w_a = fma(Eps_y[a], Eph[a][x], 1), 4 a-terms per rcp via
//   rational-sum merging, all VALU as packed-f32 over the x-pair.
// Staging combines the two split-K Eps halves + bias + exp2 for 4 rows.
__global__ void __launch_bounds__(512) attn_softmax(
    const float* __restrict__ Eph, const float* __restrict__ psPart,
    const float* __restrict__ bias, const float* __restrict__ v,
    float* __restrict__ out)
{
    int bid = blockIdx.x;            // 256 blocks = yg(32) x n(8), n minor
    int n = bid & 7, yg = bid >> 3;
    int ny = n * 128 + yg * 4;       // 4 consecutive global rows
    const f32x2* ph2 = (const f32x2*)(Eph + (size_t)n * 131072);
    int t = threadIdx.x;

    __shared__ f32x4 eps4[128];      // {Eps[y0..y3][a]}
    __shared__ f32x4 vv4[32];        // v[a] as float4
    __shared__ float wred[4][8];
    __shared__ float VsumS;

    if (t < 128) {
        f32x4 pa = *(const f32x4*)(psPart + (size_t)t * 1024 + ny);
        f32x4 pb = *(const f32x4*)(psPart + 131072 + (size_t)t * 1024 + ny);
        float bb = bias[t];
        f32x4 pk;
        #pragma unroll
        for (int j = 0; j < 4; ++j)
            pk[j] = __builtin_amdgcn_exp2f((pa[j] + pb[j] + bb) * TWO_LOG2E);
        eps4[t] = pk;
    } else if (t < 160) {
        vv4[t - 128] = *(const f32x4*)(v + (t - 128) * 4);
    }
    if (t >= 448) {                  // last wave computes Vsum (disjoint)
        int l = t - 448;
        float vv = v[l] + v[l + 64];
        for (int m = 32; m; m >>= 1) vv += __shfl_xor(vv, m);
        if (l == 0) VsumS = vv;
    }
    __syncthreads();
    float Vsum = VsumS;

    f32x2 accv[4] = {};
    f32x2 p[4]; f32x4 q[4]; f32x4 vr;
    #pragma unroll
    for (int i = 0; i < 4; ++i) p[i] = ph2[i * 512 + t];
    #pragma unroll
    for (int i = 0; i < 4; ++i) q[i] = eps4[i];
    vr = vv4[0];

    #pragma unroll 2
    for (int a = 0; a < 128; a += 4) {
        int an = (a + 4 < 128) ? a + 4 : a;          // prefetch next iter
        f32x2 np[4]; f32x4 nq[4];
        #pragma unroll
        for (int i = 0; i < 4; ++i) np[i] = ph2[(an + i) * 512 + t];
        #pragma unroll
        for (int i = 0; i < 4; ++i) nq[i] = eps4[an + i];
        f32x4 nvr = vv4[an >> 2];

        f32x2 v0 = sp2(vr[0]), v1 = sp2(vr[1]);
        f32x2 v2 = sp2(vr[2]), v3 = sp2(vr[3]);
        f32x2 one = sp2(1.f);
        // 4-term rational sum over the x-pair, packed f32:
        // 14 pk-VALU + 2 rcp covers 4 a-terms x 2 x-outputs
        #pragma unroll
        for (int j = 0; j < 4; ++j) {
            f32x2 w0 = __builtin_elementwise_fma(sp2(q[0][j]), p[0], one);
            f32x2 w1 = __builtin_elementwise_fma(sp2(q[1][j]), p[1], one);
            f32x2 w2 = __builtin_elementwise_fma(sp2(q[2][j]), p[2], one);
            f32x2 w3 = __builtin_elementwise_fma(sp2(q[3][j]), p[3], one);
            f32x2 d01 = w0 * w1, d23 = w2 * w3;
            f32x2 n01 = __builtin_elementwise_fma(v1, w0, v0 * w1);
            f32x2 n23 = __builtin_elementwise_fma(v3, w2, v2 * w3);
            f32x2 dd = d01 * d23;
            f32x2 nn = __builtin_elementwise_fma(n23, d01, n01 * d23);
            f32x2 r;
            r.x = __builtin_amdgcn_rcpf(dd.x);
            r.y = __builtin_amdgcn_rcpf(dd.y);
            accv[j] = __builtin_elementwise_fma(nn, r, accv[j]);
        }
        #pragma unroll
        for (int i = 0; i < 4; ++i) { p[i] = np[i]; q[i] = nq[i]; }
        vr = nvr;
    }

    float e[4][2];
    #pragma unroll
    for (int j = 0; j < 4; ++j) {
        e[j][0] = fmaf(-2.f, accv[j].x, Vsum);
        e[j][1] = fmaf(-2.f, accv[j].y, Vsum);
    }

    int lane = t & 63, wv = t >> 6;
    float mx[4];
    #pragma unroll
    for (int j = 0; j < 4; ++j) {
        mx[j] = fmaxf(e[j][0], e[j][1]);
        for (int m = 32; m; m >>= 1) mx[j] = fmaxf(mx[j], __shfl_xor(mx[j], m));
    }
    if (lane == 0) {
        #pragma unroll
        for (int j = 0; j < 4; ++j) wred[j][wv] = mx[j];
    }
    __syncthreads();
    #pragma unroll
    for (int j = 0; j < 4; ++j) {
        mx[j] = wred[j][0];
        #pragma unroll
        for (int i = 1; i < 8; ++i) mx[j] = fmaxf(mx[j], wred[j][i]);
    }
    __syncthreads();
    float sx[4][2], sm[4];
    #pragma unroll
    for (int j = 0; j < 4; ++j) {
        sx[j][0] = __builtin_amdgcn_exp2f((e[j][0] - mx[j]) * LOG2E);
        sx[j][1] = __builtin_amdgcn_exp2f((e[j][1] - mx[j]) * LOG2E);
        sm[j] = sx[j][0] + sx[j][1];
        for (int m = 32; m; m >>= 1) sm[j] += __shfl_xor(sm[j], m);
    }
    if (lane == 0) {
        #pragma unroll
        for (int j = 0; j < 4; ++j) wred[j][wv] = sm[j];
    }
    __syncthreads();
    #pragma unroll
    for (int j = 0; j < 4; ++j) {
        float smj = 0.f;
        #pragma unroll
        for (int i = 0; i < 8; ++i) smj += wred[j][i];
        float r = __builtin_amdgcn_rcpf(smj);
        float2 o; o.x = sx[j][0] * r; o.y = sx[j][1] * r;
        ((float2*)(out + (size_t)(ny + j) * 1024))[t] = o;
    }
}

// ----------------------------------------------------------------- launcher
extern "C" void kernel_launch(void* const* d_in, const int* in_sizes, int n_in,
                              void* d_out, int out_size, void* d_ws, size_t ws_size,
                              hipStream_t stream) {
    const float* h  = (const float*)d_in[0];
    const float* s  = (const float*)d_in[1];
    const float* Wh = (const float*)d_in[2];
    const float* Ws = (const float*)d_in[3];
    const float* b  = (const float*)d_in[4];
    const float* v  = (const float*)d_in[5];
    float* out = (float*)d_out;

    char* ws = (char*)d_ws;
    float*  Eph    = (float*)ws;                               // 4 MB
    float*  psPart = (float*)(ws + (4u << 20));                // 1 MB (2 halves)
    __bf16* WhT    = (__bf16*)(ws + (5u << 20));               // 128 KB
    __bf16* WsT    = WhT + (size_t)128 * 512;                  // 256 KB

    transpose_cast<<<96, 256, 0, stream>>>(Wh, Ws, WhT, WsT);
    gemm_fused<<<640, 256, 0, stream>>>(WhT, WsT, h, s, Eph, psPart);
    attn_softmax<<<256, 512, 0, stream>>>(Eph, psPart, b, v, out);
}